// Round 4
// baseline (70.238 us; speedup 1.0000x reference)
//
#include <hip/hip_runtime.h>
#include <math.h>

#define HH 512
#define WW 512
#define M 2048          // 64 segs * 32 samples = path points / edges
#define TPB 256
#define TWL 15          // window left half-width: A = floor(xc) - TWL
#define WPIX 32         // window pixels; truncation error <= e^-16 per edge
#define EPB 8           // 8 edges per dense pass (8*32 = 256 lanes, none idle)

// fast sigmoid: v_exp + v_rcp (1-ulp rcp; error budget has ~5x margin)
__device__ __forceinline__ float sigmoidf(float z) {
    return __builtin_amdgcn_rcpf(1.0f + __expf(-z));
}

__global__ __launch_bounds__(TPB) void bezier_render_kernel(
    const float* __restrict__ cp,     // 193*2 floats
    const float* __restrict__ color,  // 3 floats
    float* __restrict__ out)          // H*W*4 floats, channel-last
{
    __shared__ float2 pts[M];          // 16 KB sampled path
    __shared__ int    cand[M];         // 8 KB candidate edge ids (range-test pass)
    __shared__ float2 act[M];          // 16 KB compacted (x_cross, w)
    __shared__ float  smoothv[WW];     // windowed (exact) sigmoid part
    __shared__ float  cbin[WW + 1];    // step-part bins
    __shared__ float  wtot[4];         // per-wave scan totals
    __shared__ int    ncand, nact;
    // total ~45 KB -> 3 blocks/CU

    const int t    = threadIdx.x;
    const int lane = t & 63;
    const int wv   = t >> 6;
    const int y    = blockIdx.x;
    const float gy = (float)y;

    // ---- 0) init accumulators (no cps2 stage; cp read direct from L1/L2) ----
    if (t == 0) { ncand = 0; nact = 0; cbin[WW] = 0.0f; }
    for (int x = t; x < WW; x += TPB) { smoothv[x] = 0.0f; cbin[x] = 0.0f; }

    // ---- 1) sample cubic beziers: 4 threads/segment, 8 samples each ----
    // Control points loaded once per thread from global (1.5 KB, cache-hot);
    // pairs of points written as one b128. Same weights/fma expressions as
    // before -> identical pts[] values.
    {
        const float2* cp2 = (const float2*)cp;
        int s  = t >> 2;                 // segment 0..63
        int j0 = (t & 3) << 3;           // first sample 0/8/16/24
        float2 P0 = cp2[3 * s],     P1 = cp2[3 * s + 1];
        float2 P2 = cp2[3 * s + 2], P3 = cp2[3 * s + 3];
        float4* pts4 = (float4*)&pts[(s << 5) + j0];   // 64B-aligned
#pragma unroll
        for (int jj = 0; jj < 8; jj += 2) {
            float2 q0, q1;
#pragma unroll
            for (int u2 = 0; u2 < 2; ++u2) {
                float tt = (float)(j0 + jj + u2) * (1.0f / 31.0f);
                float mt = 1.0f - tt;
                float w0 = mt * mt * mt;
                float w1 = 3.0f * mt * mt * tt;
                float w2 = 3.0f * mt * tt * tt;
                float w3 = tt * tt * tt;
                float2 q = make_float2(w0 * P0.x + w1 * P1.x + w2 * P2.x + w3 * P3.x,
                                       w0 * P0.y + w1 * P1.y + w2 * P2.y + w3 * P3.y);
                if (u2 == 0) q0 = q; else q1 = q;
            }
            pts4[jj >> 1] = make_float4(q0.x, q0.y, q1.x, q1.y);
        }
    }
    __syncthreads();

    // ---- 2a pass 1: rcp-free range test, compact candidate edge ids ----
    // valid_t < 1e-7 outside tc in (-0.8059, 1.8059); test u against
    // (min,max)(-0.8059d, 1.8059d) with multiplies only. ~5% of edges pass,
    // so the expensive body is deferred to a dense pass (pass 2) instead of
    // running exec-masked on ~every wave-iteration here.
    for (int e = t; e < M; e += TPB) {
        float2 a = pts[e];
        float2 b = pts[(e + 1) & (M - 1)];
        float dy = b.y - a.y;
        if (!(fabsf(dy) >= 1e-6f)) continue;
        float d  = dy + 1e-8f;
        float u  = gy - a.y;
        float g0 = -0.8059f * d;
        float g1 =  1.8059f * d;
        if (!(u > fminf(g0, g1)) || !(u < fmaxf(g0, g1))) continue;
        int idx = atomicAdd(&ncand, 1);      // wave-aggregated by compiler
        cand[idx] = e;
    }
    __syncthreads();

    // ---- 2a pass 2: dense transcendental pass over ~110 candidates ----
    // Identical math to the old fused body (accept set and values bit-equal).
    {
        int nc = ncand;
        for (int c = t; c < nc; c += TPB) {
            int e = cand[c];
            float2 a = pts[e];
            float2 b = pts[(e + 1) & (M - 1)];
            float dy = b.y - a.y;
            float d  = dy + 1e-8f;
            float tc = (gy - a.y) * __builtin_amdgcn_rcpf(d);
            float ea = __expf(-20.0f * tc);
            float eb = __expf(-20.0f * (1.0f - tc));
            float v  = __builtin_amdgcn_rcpf((1.0f + ea) * (1.0f + eb));
            float w  = (dy > 0.0f) ? v : -v;             // valid_t * sign(dy)
            float xc = fmaf(tc, b.x - a.x, a.x);
            int A = (int)floorf(xc) - TWL;               // first windowed pixel
            int bin = (A > WW) ? WW : A;                 // pixels x<A get full w
            if (bin > 0) atomicAdd(&cbin[bin], w);
            if (A < WW && A > -WPIX) {                   // window overlaps the row
                int idx = atomicAdd(&nact, 1);
                act[idx] = make_float2(xc, w);
            }
        }
    }
    __syncthreads();

    // ---- 2b) dense windowed pass: 32 lanes per active edge, 8 edges/pass ----
    {
        int na = nact;
        int el = t >> 5;                 // 0..7
        int k  = t & 31;                 // 0..31
        for (int e = el; e < na; e += EPB) {
            float2 xw = act[e];
            int x = (int)floorf(xw.x) - TWL + k;
            if ((unsigned)x < (unsigned)WW) {
                atomicAdd(&smoothv[x], xw.y * sigmoidf(xw.x - (float)x));
            }
        }
    }
    __syncthreads();

    // ---- 3) suffix scan of cbin: wind_const[x] = sum_{j>x} cbin[j] ----
    // shfl-based in-wave inclusive suffix scan (no barriers), then combine
    // 4 wave totals through LDS with a single barrier.
    float e0 = cbin[2 * t];
    float e1 = cbin[2 * t + 1];
    float p  = e0 + e1;
    float v  = p;
#pragma unroll
    for (int off = 1; off < 64; off <<= 1) {
        float o = __shfl_down(v, off, 64);
        if (lane + off < 64) v += o;
    }
    if (lane == 0) wtot[wv] = v;         // wave total = suffix at its first lane
    __syncthreads();
    float hsum = 0.0f;
    if (wv < 1) hsum += wtot[1];
    if (wv < 2) hsum += wtot[2];
    if (wv < 3) hsum += wtot[3];
    float S    = v - p + hsum;           // sum of p(u) for threads u > t
    float c512 = cbin[WW];
    float wc1  = S + c512;               // wind_const at x=2t+1
    float wc0  = e1 + wc1;               // wind_const at x=2t

    // ---- 4) alpha + output ----
    float r = color[0], g = color[1], bl = color[2];
    int x0 = 2 * t;
    float a0 = sigmoidf(4.0f * (wc0 + smoothv[x0]));
    float a1 = sigmoidf(4.0f * (wc1 + smoothv[x0 + 1]));
    float4* out4 = (float4*)out;
    out4[y * WW + x0]     = make_float4(r, g, bl, a0);
    out4[y * WW + x0 + 1] = make_float4(r, g, bl, a1);
}

extern "C" void kernel_launch(void* const* d_in, const int* in_sizes, int n_in,
                              void* d_out, int out_size, void* d_ws, size_t ws_size,
                              hipStream_t stream) {
    const float* cp    = (const float*)d_in[0];  // (193,2) float32
    const float* color = (const float*)d_in[1];  // (3,) float32
    float* out = (float*)d_out;                  // (512,512,4) float32
    bezier_render_kernel<<<dim3(HH), dim3(TPB), 0, stream>>>(cp, color, out);
}

// Round 5
// 69.399 us; speedup vs baseline: 1.0121x; 1.0121x over previous
//
#include <hip/hip_runtime.h>
#include <math.h>

#define HH 512
#define WW 512
#define M 2048          // 64 segs * 32 samples = path points / edges
#define TPB 256
#define TWL 15          // window left half-width: A = floor(xc) - TWL
#define WPIX 32         // window pixels; truncation error <= e^-16 per edge
#define EPB 8           // 8 edges per dense pass (8*32 = 256 lanes, none idle)

// fast sigmoid: v_exp + v_rcp (1-ulp rcp; error budget has ~5x margin)
__device__ __forceinline__ float sigmoidf(float z) {
    return __builtin_amdgcn_rcpf(1.0f + __expf(-z));
}

__global__ __launch_bounds__(TPB) void bezier_render_kernel(
    const float* __restrict__ cp,     // 193*2 floats
    const float* __restrict__ color,  // 3 floats
    float* __restrict__ out)          // H*W*4 floats, channel-last
{
    __shared__ float2 pts[M];          // 16 KB sampled path
    __shared__ float  smoothv[WW];     // windowed (exact) sigmoid part
    __shared__ float  cbin[WW + 1];    // step-part bins
    __shared__ float  wtot[4];         // per-wave scan totals
    __shared__ float2 act[M];          // compacted (x_cross, w)
    __shared__ int    nact;

    const int t    = threadIdx.x;
    const int lane = t & 63;
    const int wv   = t >> 6;
    const int y    = blockIdx.x;
    const float gy = (float)y;

    // ---- 0) init accumulators (no cps2 stage; cp read direct from L1/L2) ----
    if (t == 0) { nact = 0; cbin[WW] = 0.0f; }
    for (int x = t; x < WW; x += TPB) { smoothv[x] = 0.0f; cbin[x] = 0.0f; }

    // ---- 1) sample cubic beziers: 4 threads/segment, 8 samples each ----
    // Control points loaded once per thread from global (1.5 KB, cache-hot);
    // pairs of points written as one b128. Same weight/fma expressions as the
    // original sampler -> identical pts[] values. No staging barrier needed.
    {
        const float2* cp2 = (const float2*)cp;
        int s  = t >> 2;                 // segment 0..63
        int j0 = (t & 3) << 3;           // first sample 0/8/16/24
        float2 P0 = cp2[3 * s],     P1 = cp2[3 * s + 1];
        float2 P2 = cp2[3 * s + 2], P3 = cp2[3 * s + 3];
        float4* pts4 = (float4*)&pts[(s << 5) + j0];   // 64B-aligned
#pragma unroll
        for (int jj = 0; jj < 8; jj += 2) {
            float2 q0, q1;
#pragma unroll
            for (int u2 = 0; u2 < 2; ++u2) {
                float tt = (float)(j0 + jj + u2) * (1.0f / 31.0f);
                float mt = 1.0f - tt;
                float w0 = mt * mt * mt;
                float w1 = 3.0f * mt * mt * tt;
                float w2 = 3.0f * mt * tt * tt;
                float w3 = tt * tt * tt;
                float2 q = make_float2(w0 * P0.x + w1 * P1.x + w2 * P2.x + w3 * P3.x,
                                       w0 * P0.y + w1 * P1.y + w2 * P2.y + w3 * P3.y);
                if (u2 == 0) q0 = q; else q1 = q;
            }
            pts4[jj >> 1] = make_float4(q0.x, q0.y, q1.x, q1.y);
        }
    }
    __syncthreads();

    // ---- 2a) fused edge scan: rcp-free EARLY REJECT, then transcendental body ----
    // valid_t < 1e-7 is implied by tc outside (-0.8059, 1.8059):
    // sigmoid(20*(-0.8059)) = 9.96e-8. Test u against (min,max)(-0.8059d,
    // 1.8059d) with multiplies only; rcp/exp only for accepted (~5%) pairs.
    // (Two-pass compaction measured neutral-to-worse: barrier + LDS round-trip
    // costs more than the exec-masked body at this density — R4 post-mortem.)
    for (int e = t; e < M; e += TPB) {
        float2 a = pts[e];
        float2 b = pts[(e + 1) & (M - 1)];
        float dy = b.y - a.y;
        if (!(fabsf(dy) >= 1e-6f)) continue;
        float d  = dy + 1e-8f;
        float u  = gy - a.y;
        float g0 = -0.8059f * d;
        float g1 =  1.8059f * d;
        if (!(u > fminf(g0, g1)) || !(u < fmaxf(g0, g1))) continue;
        float tc = u * __builtin_amdgcn_rcpf(d);
        float ea = __expf(-20.0f * tc);
        float eb = __expf(-20.0f * (1.0f - tc));
        float v = __builtin_amdgcn_rcpf((1.0f + ea) * (1.0f + eb));
        float w = (dy > 0.0f) ? v : -v;                 // valid_t * sign(dy)
        float xc = fmaf(tc, b.x - a.x, a.x);
        int A = (int)floorf(xc) - TWL;                  // first windowed pixel
        int bin = (A > WW) ? WW : A;                    // pixels x<A get full w
        if (bin > 0) atomicAdd(&cbin[bin], w);
        if (A < WW && A > -WPIX) {                      // window overlaps the row
            int idx = atomicAdd(&nact, 1);              // wave-aggregated by compiler
            act[idx] = make_float2(xc, w);
        }
    }
    __syncthreads();

    // ---- 2b) dense windowed pass: 32 lanes per active edge, 8 edges/pass ----
    {
        int na = nact;
        int el = t >> 5;                 // 0..7
        int k  = t & 31;                 // 0..31
        for (int e = el; e < na; e += EPB) {
            float2 xw = act[e];
            int x = (int)floorf(xw.x) - TWL + k;
            if ((unsigned)x < (unsigned)WW) {
                atomicAdd(&smoothv[x], xw.y * sigmoidf(xw.x - (float)x));
            }
        }
    }
    __syncthreads();

    // ---- 3) suffix scan of cbin: wind_const[x] = sum_{j>x} cbin[j] ----
    // shfl-based in-wave inclusive suffix scan (no barriers), then combine
    // 4 wave totals through LDS with a single barrier.
    float e0 = cbin[2 * t];
    float e1 = cbin[2 * t + 1];
    float p  = e0 + e1;
    float v  = p;
#pragma unroll
    for (int off = 1; off < 64; off <<= 1) {
        float o = __shfl_down(v, off, 64);
        if (lane + off < 64) v += o;
    }
    if (lane == 0) wtot[wv] = v;         // wave total = suffix at its first lane
    __syncthreads();
    float hsum = 0.0f;
    if (wv < 1) hsum += wtot[1];
    if (wv < 2) hsum += wtot[2];
    if (wv < 3) hsum += wtot[3];
    float S    = v - p + hsum;           // sum of p(u) for threads u > t
    float c512 = cbin[WW];
    float wc1  = S + c512;               // wind_const at x=2t+1
    float wc0  = e1 + wc1;               // wind_const at x=2t

    // ---- 4) alpha + output ----
    float r = color[0], g = color[1], bl = color[2];
    int x0 = 2 * t;
    float a0 = sigmoidf(4.0f * (wc0 + smoothv[x0]));
    float a1 = sigmoidf(4.0f * (wc1 + smoothv[x0 + 1]));
    float4* out4 = (float4*)out;
    out4[y * WW + x0]     = make_float4(r, g, bl, a0);
    out4[y * WW + x0 + 1] = make_float4(r, g, bl, a1);
}

extern "C" void kernel_launch(void* const* d_in, const int* in_sizes, int n_in,
                              void* d_out, int out_size, void* d_ws, size_t ws_size,
                              hipStream_t stream) {
    const float* cp    = (const float*)d_in[0];  // (193,2) float32
    const float* color = (const float*)d_in[1];  // (3,) float32
    float* out = (float*)d_out;                  // (512,512,4) float32
    bezier_render_kernel<<<dim3(HH), dim3(TPB), 0, stream>>>(cp, color, out);
}